// Round 1
// baseline (914.434 us; speedup 1.0000x reference)
//
#include <hip/hip_runtime.h>

typedef unsigned short u16;
typedef unsigned int u32;
typedef unsigned long long u64;
typedef __attribute__((ext_vector_type(8))) short short8;
typedef __attribute__((ext_vector_type(4))) float f32x4;

#define NB 64
#define LL 4096
#define CC 512
#define KK 2048     // kept tokens
#define PPQ 819     // P
#define HH 102      // H
#define KP 2176     // padded rows (2049 -> 17*128)
#define PPAD 896    // padded P (7*128)
#define HP 112      // padded H for h buffer

__device__ __forceinline__ u16 f2bf(float f) {
  u32 u = __float_as_uint(f);
  u += 0x7fffu + ((u >> 16) & 1u);
  return (u16)(u >> 16);
}
__device__ __forceinline__ float bf2f(u16 h) { return __uint_as_float(((u32)h) << 16); }
__device__ __forceinline__ float dec_score(u32 s) {
  u32 u = (s & 0x80000000u) ? (s ^ 0x80000000u) : ~s;
  return __uint_as_float(u);
}

// ---------- per-batch bitonic sort of composite keys + mask + tail-softmax stats ----------
__global__ __launch_bounds__(1024) void sort_kernel(
    const float* __restrict__ ax, const float* __restrict__ ay,
    u64* __restrict__ keys, float* __restrict__ mask_out, float2* __restrict__ stats)
{
  __shared__ u64 arr[LL];
  __shared__ float red[16];
  int b = blockIdx.x, tid = threadIdx.x;
  for (int i = tid; i < LL; i += 1024) {
    float s = ax[(size_t)b*LL + i] + ay[(size_t)b*LL + i];
    u32 u = __float_as_uint(s);
    u = (u & 0x80000000u) ? ~u : (u | 0x80000000u);
    arr[i] = (((u64)u) << 32) | (u32)(LL - 1 - i);
  }
  __syncthreads();
  for (int k = 2; k <= LL; k <<= 1) {
    for (int j = k >> 1; j > 0; j >>= 1) {
      #pragma unroll
      for (int rep = 0; rep < 4; ++rep) {
        int i = tid + rep * 1024;
        int ixj = i ^ j;
        if (ixj > i) {
          u64 a = arr[i], c = arr[ixj];
          bool desc = ((i & k) == 0);
          if (desc ? (a < c) : (a > c)) { arr[i] = c; arr[ixj] = a; }
        }
      }
      __syncthreads();
    }
  }
  for (int i = tid; i < LL; i += 1024) {
    u64 v = arr[i];
    keys[(size_t)b*LL + i] = v;
    int idx = (LL - 1) - (int)(v & 0xffffffffu);
    mask_out[(size_t)b*LL + idx] = (i < KK) ? 1.0f : 0.0f;
  }
  // tail softmax stats: max is first tail element (descending sort)
  float m = dec_score((u32)(arr[KK] >> 32));
  float part = 0.f;
  for (int i = KK + tid; i < LL; i += 1024)
    part += expf(dec_score((u32)(arr[i] >> 32)) - m);
  #pragma unroll
  for (int off = 32; off; off >>= 1) part += __shfl_xor(part, off);
  if ((tid & 63) == 0) red[tid >> 6] = part;
  __syncthreads();
  if (tid == 0) {
    float s = 0.f;
    #pragma unroll
    for (int i = 0; i < 16; ++i) s += red[i];
    stats[b] = make_float2(m, s);
  }
}

// ---------- tail weighted partial sums (extra token) ----------
__global__ __launch_bounds__(256) void tail_partial_kernel(
    const float* __restrict__ tokens, const u64* __restrict__ keys,
    const float2* __restrict__ stats, float* __restrict__ partials)
{
  int b = blockIdx.y, rb = blockIdx.x, t = threadIdx.x;
  float m = stats[b].x, inv = 1.0f / stats[b].y;
  const u64* kb = keys + (size_t)b*LL + KK + rb*256;
  float a0 = 0.f, a1 = 0.f;
  #pragma unroll 4
  for (int r = 0; r < 256; ++r) {
    u64 kk = kb[r];
    int idx = (LL - 1) - (int)(kk & 0xffffffffu);
    float w = expf(dec_score((u32)(kk >> 32)) - m) * inv;
    const float* src = tokens + ((size_t)b*LL + idx)*CC;
    a0 += w * src[t];
    a1 += w * src[t + 256];
  }
  float* dst = partials + (size_t)(b*8 + rb)*CC;
  dst[t] = a0; dst[t + 256] = a1;
}

// ---------- gather all_tokens (bf16) + per-row LN stats ----------
__global__ __launch_bounds__(256) void gather_ln_kernel(
    const float* __restrict__ tokens, const u64* __restrict__ keys,
    const float* __restrict__ partials,
    u16* __restrict__ allT, float2* __restrict__ rowstats)
{
  int b = blockIdx.y;
  int r = blockIdx.x*4 + (threadIdx.x >> 6);
  int lane = threadIdx.x & 63;
  size_t orow = ((size_t)b*KP + r)*CC;
  int c0 = lane*8;
  if (r > KK) {  // zero padding rows
    short8 z = {};
    *(short8*)(allT + orow + c0) = z;
    if (lane == 0) rowstats[(size_t)b*KP + r] = make_float2(0.f, 0.f);
    return;
  }
  float x[8];
  if (r < KK) {
    u64 kk = keys[(size_t)b*LL + r];
    int idx = (LL - 1) - (int)(kk & 0xffffffffu);
    const float* src = tokens + ((size_t)b*LL + idx)*CC + c0;
    f32x4 v0 = *(const f32x4*)src;
    f32x4 v1 = *(const f32x4*)(src + 4);
    #pragma unroll
    for (int j = 0; j < 4; ++j) { x[j] = v0[j]; x[j+4] = v1[j]; }
  } else {  // r == KK: extra token = sum of 8 partials
    #pragma unroll
    for (int j = 0; j < 8; ++j) {
      float s = 0.f;
      #pragma unroll
      for (int p = 0; p < 8; ++p) s += partials[(size_t)(b*8 + p)*CC + c0 + j];
      x[j] = s;
    }
  }
  float s = 0.f;
  #pragma unroll
  for (int j = 0; j < 8; ++j) s += x[j];
  #pragma unroll
  for (int off = 32; off; off >>= 1) s += __shfl_xor(s, off);
  float mu = s * (1.0f/CC);
  float vs = 0.f;
  #pragma unroll
  for (int j = 0; j < 8; ++j) { float d = x[j] - mu; vs += d*d; }
  #pragma unroll
  for (int off = 32; off; off >>= 1) vs += __shfl_xor(vs, off);
  float rstd = rsqrtf(vs * (1.0f/CC) + 1e-5f);
  short8 raw;
  #pragma unroll
  for (int j = 0; j < 8; ++j) raw[j] = (short)f2bf(x[j]);
  *(short8*)(allT + orow + c0) = raw;
  if (lane == 0) rowstats[(size_t)b*KP + r] = make_float2(mu, rstd);
}

// ---------- weights -> padded bf16 ----------
__global__ __launch_bounds__(256) void prep_kernel(
    const float* __restrict__ w1, const float* __restrict__ w2,
    u16* __restrict__ w1p, u16* __restrict__ w2p)
{
  int id = blockIdx.x*256 + threadIdx.x;
  if (id < 512*128) {
    int r = id >> 7, c = id & 127;
    w1p[id] = (c < HH) ? f2bf(w1[r*HH + c]) : (u16)0;
  } else {
    int id2 = id - 512*128;
    if (id2 < HP*PPAD) {
      int r = id2 / PPAD, c = id2 - r*PPAD;
      w2p[id2] = (r < HH && c < PPQ) ? f2bf(w2[(size_t)r*PPQ + c]) : (u16)0;
    }
  }
}

// ---------- generic 128x128x32 bf16 MFMA GEMM, MODE-specific epilogues ----------
// MODE 0: A=allT (LN fused via rowstats/g/b), B=w1p -> h = bf16(gelu(.+b1)), cols>=HH zeroed
// MODE 1: A=h(batch), B=w2p -> wgt[p][k] = bf16((.+b2[p])*scale)  (transposed store)
// MODE 2: A=wgt(batch), B=allT(batch) -> out fp32, rows p<819
template<int MODE>
__global__ __launch_bounds__(256) void gemm_kernel(
    const u16* __restrict__ A, const u16* __restrict__ Bm, void* __restrict__ Cv,
    const float* __restrict__ bias, const float* __restrict__ scalep,
    const float2* __restrict__ rowstats,
    const float* __restrict__ gvec, const float* __restrict__ bvec,
    int lda, int ldb, int Ksteps, int Kbound)
{
  __shared__ u16 As[128][40];
  __shared__ u16 Bs[32][136];
  int b = blockIdx.z;
  const u16* Ab = A; const u16* Bb = Bm;
  if (MODE == 1) { Ab = A + (size_t)b*KP*HP; }
  if (MODE == 2) { Ab = A + (size_t)b*PPAD*KP; Bb = Bm + (size_t)b*KP*CC; }
  int m0 = blockIdx.x*128, n0 = blockIdx.y*128;
  int tid = threadIdx.x, lane = tid & 63, wave = tid >> 6;
  int wr = (wave >> 1)*64, wc = (wave & 1)*64;
  int ar0 = tid >> 2, ac0 = (tid & 3)*8;
  int ar1 = ar0 + 64;
  int bk0 = tid >> 4, bn0 = (tid & 15)*8;
  int bk1 = bk0 + 16;
  float2 st0 = make_float2(0.f, 0.f), st1 = st0;
  if (MODE == 0) { st0 = rowstats[m0 + ar0]; st1 = rowstats[m0 + ar1]; }
  f32x4 acc[4][4];
  #pragma unroll
  for (int m = 0; m < 4; ++m)
    #pragma unroll
    for (int n = 0; n < 4; ++n) acc[m][n] = (f32x4){0.f, 0.f, 0.f, 0.f};

  for (int ks = 0; ks < Ksteps; ++ks) {
    int k0 = ks*32;
    {
      short8 v = {};
      if (k0 + ac0 < Kbound) v = *(const short8*)(Ab + (size_t)(m0 + ar0)*lda + k0 + ac0);
      if (MODE == 0) {
        short8 o;
        #pragma unroll
        for (int j = 0; j < 8; ++j) {
          int kc = k0 + ac0 + j;
          o[j] = (short)f2bf((bf2f((u16)v[j]) - st0.x)*st0.y*gvec[kc] + bvec[kc]);
        }
        v = o;
      }
      *(short8*)(&As[ar0][ac0]) = v;
      short8 v2 = {};
      if (k0 + ac0 < Kbound) v2 = *(const short8*)(Ab + (size_t)(m0 + ar1)*lda + k0 + ac0);
      if (MODE == 0) {
        short8 o;
        #pragma unroll
        for (int j = 0; j < 8; ++j) {
          int kc = k0 + ac0 + j;
          o[j] = (short)f2bf((bf2f((u16)v2[j]) - st1.x)*st1.y*gvec[kc] + bvec[kc]);
        }
        v2 = o;
      }
      *(short8*)(&As[ar1][ac0]) = v2;
    }
    {
      short8 v = {};
      if (k0 + bk0 < Kbound) v = *(const short8*)(Bb + (size_t)(k0 + bk0)*ldb + n0 + bn0);
      *(short8*)(&Bs[bk0][bn0]) = v;
      short8 v2 = {};
      if (k0 + bk1 < Kbound) v2 = *(const short8*)(Bb + (size_t)(k0 + bk1)*ldb + n0 + bn0);
      *(short8*)(&Bs[bk1][bn0]) = v2;
    }
    __syncthreads();
    const u16* ap = &As[wr + (lane & 15)][(lane >> 4)*8];
    short8 af[4];
    #pragma unroll
    for (int m = 0; m < 4; ++m) af[m] = *(const short8*)(ap + m*16*40);
    int kbase = (lane >> 4)*8;
    int cb = wc + (lane & 15);
    #pragma unroll
    for (int n = 0; n < 4; ++n) {
      short8 bfv;
      #pragma unroll
      for (int j = 0; j < 8; ++j) bfv[j] = (short)Bs[kbase + j][cb + n*16];
      #pragma unroll
      for (int m = 0; m < 4; ++m)
        acc[m][n] = __builtin_amdgcn_mfma_f32_16x16x32_bf16(af[m], bfv, acc[m][n], 0, 0, 0);
    }
    __syncthreads();
  }
  float sc = (MODE == 1) ? scalep[0] : 1.0f;
  #pragma unroll
  for (int m = 0; m < 4; ++m) {
    #pragma unroll
    for (int n = 0; n < 4; ++n) {
      #pragma unroll
      for (int q = 0; q < 4; ++q) {
        int gm = m0 + wr + m*16 + (lane >> 4)*4 + q;
        int gn = n0 + wc + n*16 + (lane & 15);
        float v = acc[m][n][q];
        if (MODE == 0) {
          if (gn < HP) {
            float r = 0.f;
            if (gn < HH) { float xx = v + bias[gn]; r = 0.5f*xx*(1.0f + erff(xx*0.70710678118654752f)); }
            ((u16*)Cv)[(size_t)gm*HP + gn] = f2bf(r);
          }
        } else if (MODE == 1) {
          if (gn < PPQ) ((u16*)Cv)[(size_t)b*PPAD*KP + (size_t)gn*KP + gm] = f2bf((v + bias[gn])*sc);
        } else {
          if (gm < PPQ) ((float*)Cv)[(size_t)b*PPQ*CC + (size_t)gm*CC + gn] = v;
        }
      }
    }
  }
}

// ---------- row softmax over k (in place, bf16), zero padding ----------
__global__ __launch_bounds__(256) void softmax_kernel(u16* __restrict__ wgt) {
  int b = blockIdx.y, p = blockIdx.x, tid = threadIdx.x;
  u16* row = wgt + ((size_t)b*PPAD + p)*KP;
  if (p >= PPQ) {
    for (int k = tid; k < KP; k += 256) row[k] = 0;
    return;
  }
  __shared__ float red[4];
  float vals[9];
  float mx = -3.4e38f;
  #pragma unroll
  for (int i = 0; i < 9; ++i) {
    int k = tid + i*256;
    if (k <= KK) { vals[i] = bf2f(row[k]); mx = fmaxf(mx, vals[i]); }
  }
  #pragma unroll
  for (int off = 32; off; off >>= 1) mx = fmaxf(mx, __shfl_xor(mx, off));
  if ((tid & 63) == 0) red[tid >> 6] = mx;
  __syncthreads();
  mx = fmaxf(fmaxf(red[0], red[1]), fmaxf(red[2], red[3]));
  __syncthreads();
  float s = 0.f;
  #pragma unroll
  for (int i = 0; i < 9; ++i) {
    int k = tid + i*256;
    if (k <= KK) { vals[i] = expf(vals[i] - mx); s += vals[i]; }
  }
  #pragma unroll
  for (int off = 32; off; off >>= 1) s += __shfl_xor(s, off);
  if ((tid & 63) == 0) red[tid >> 6] = s;
  __syncthreads();
  float invs = 1.0f / (red[0] + red[1] + red[2] + red[3]);
  #pragma unroll
  for (int i = 0; i < 9; ++i) {
    int k = tid + i*256;
    if (k <= KK) row[k] = f2bf(vals[i] * invs);
    else if (k < KP) row[k] = 0;
  }
}

extern "C" void kernel_launch(void* const* d_in, const int* in_sizes, int n_in,
                              void* d_out, int out_size, void* d_ws, size_t ws_size,
                              hipStream_t stream)
{
  const float* tokens = (const float*)d_in[0];
  const float* ax  = (const float*)d_in[1];
  const float* ay  = (const float*)d_in[2];
  const float* ln_g = (const float*)d_in[3];
  const float* ln_b = (const float*)d_in[4];
  const float* w1  = (const float*)d_in[5];
  const float* b1  = (const float*)d_in[6];
  const float* w2  = (const float*)d_in[7];
  const float* b2  = (const float*)d_in[8];
  const float* scale = (const float*)d_in[9];
  float* out_super = (float*)d_out;
  float* out_mask  = out_super + (size_t)NB*PPQ*CC;

  char* ws = (char*)d_ws;
  size_t off = 0;
  u64* keys = (u64*)(ws + off);        off += (size_t)NB*LL*8;
  float2* stats = (float2*)(ws + off); off += (size_t)NB*sizeof(float2);
  off = (off + 255) & ~(size_t)255;
  float* partials = (float*)(ws + off); off += (size_t)NB*8*CC*4;
  off = (off + 255) & ~(size_t)255;
  float2* rowstats = (float2*)(ws + off); off += (size_t)NB*KP*8;
  off = (off + 255) & ~(size_t)255;
  u16* allT = (u16*)(ws + off); off += (size_t)NB*KP*CC*2;
  u16* hbuf = (u16*)(ws + off); off += (size_t)NB*KP*HP*2;
  u16* wgt  = (u16*)(ws + off); off += (size_t)NB*PPAD*KP*2;
  u16* w1p  = (u16*)(ws + off); off += (size_t)512*128*2;
  u16* w2p  = (u16*)(ws + off); off += (size_t)HP*PPAD*2;
  if (off > ws_size) return;  // workspace too small -> visible failure

  prep_kernel<<<648, 256, 0, stream>>>(w1, w2, w1p, w2p);
  sort_kernel<<<NB, 1024, 0, stream>>>(ax, ay, keys, out_mask, stats);
  tail_partial_kernel<<<dim3(8, NB), 256, 0, stream>>>(tokens, keys, stats, partials);
  gather_ln_kernel<<<dim3(KP/4, NB), 256, 0, stream>>>(tokens, keys, partials, allT, rowstats);
  gemm_kernel<0><<<dim3((NB*KP)/128, 1, 1), 256, 0, stream>>>(
      allT, w1p, hbuf, b1, scale, rowstats, ln_g, ln_b, CC, 128, 16, CC);
  gemm_kernel<1><<<dim3(KP/128, PPAD/128, NB), 256, 0, stream>>>(
      hbuf, w2p, wgt, b2, scale, nullptr, nullptr, nullptr, HP, PPAD, 4, HP);
  softmax_kernel<<<dim3(PPAD, NB), 256, 0, stream>>>(wgt);
  gemm_kernel<2><<<dim3(PPAD/128, CC/128, NB), 256, 0, stream>>>(
      wgt, allT, out_super, nullptr, scale, nullptr, nullptr, nullptr, KP, CC, KP/32, KP);
}

// Round 2
// 637.753 us; speedup vs baseline: 1.4338x; 1.4338x over previous
//
#include <hip/hip_runtime.h>

typedef unsigned short u16;
typedef unsigned int u32;
typedef unsigned long long u64;
typedef __attribute__((ext_vector_type(8))) short short8;
typedef __attribute__((ext_vector_type(4))) float f32x4;

#define NB 64
#define LL 4096
#define CC 512
#define KK 2048     // kept tokens (extra token at row KK)
#define PPQ 819     // P
#define HH 102      // H
#define KP 2176     // padded all_tokens rows (17*128)
#define PPAD 896    // padded P (7*128)
#define HP 128      // padded H

__device__ __forceinline__ u16 f2bf(float f) {
  u32 u = __float_as_uint(f);
  u += 0x7fffu + ((u >> 16) & 1u);
  return (u16)(u >> 16);
}
__device__ __forceinline__ float bf2f(u16 h) { return __uint_as_float(((u32)h) << 16); }
__device__ __forceinline__ float dec_score(u32 s) {
  u32 u = (s & 0x80000000u) ? (s ^ 0x80000000u) : ~s;
  return __uint_as_float(u);
}

typedef __attribute__((address_space(1))) void gvoid;
typedef __attribute__((address_space(3))) void lvoid;
__device__ __forceinline__ void gload16(const u16* g, u16* l) {
  __builtin_amdgcn_global_load_lds((gvoid*)(g), (lvoid*)(l), 16, 0, 0);
}

// ---------- per-batch bitonic sort of composite keys + mask + tail-softmax stats ----------
__global__ __launch_bounds__(1024) void sort_kernel(
    const float* __restrict__ ax, const float* __restrict__ ay,
    u64* __restrict__ keys, float* __restrict__ mask_out, float2* __restrict__ stats)
{
  __shared__ u64 arr[LL];
  __shared__ float red[16];
  int b = blockIdx.x, tid = threadIdx.x;
  for (int i = tid; i < LL; i += 1024) {
    float s = ax[(size_t)b*LL + i] + ay[(size_t)b*LL + i];
    u32 u = __float_as_uint(s);
    u = (u & 0x80000000u) ? ~u : (u | 0x80000000u);
    arr[i] = (((u64)u) << 32) | (u32)(LL - 1 - i);
  }
  __syncthreads();
  for (int k = 2; k <= LL; k <<= 1) {
    for (int j = k >> 1; j > 0; j >>= 1) {
      #pragma unroll
      for (int rep = 0; rep < 4; ++rep) {
        int i = tid + rep * 1024;
        int ixj = i ^ j;
        if (ixj > i) {
          u64 a = arr[i], c = arr[ixj];
          bool desc = ((i & k) == 0);
          if (desc ? (a < c) : (a > c)) { arr[i] = c; arr[ixj] = a; }
        }
      }
      __syncthreads();
    }
  }
  for (int i = tid; i < LL; i += 1024) {
    u64 v = arr[i];
    keys[(size_t)b*LL + i] = v;
    int idx = (LL - 1) - (int)(v & 0xffffffffu);
    mask_out[(size_t)b*LL + idx] = (i < KK) ? 1.0f : 0.0f;
  }
  float m = dec_score((u32)(arr[KK] >> 32));
  float part = 0.f;
  for (int i = KK + tid; i < LL; i += 1024)
    part += expf(dec_score((u32)(arr[i] >> 32)) - m);
  #pragma unroll
  for (int off = 32; off; off >>= 1) part += __shfl_xor(part, off);
  if ((tid & 63) == 0) red[tid >> 6] = part;
  __syncthreads();
  if (tid == 0) {
    float s = 0.f;
    #pragma unroll
    for (int i = 0; i < 16; ++i) s += red[i];
    stats[b] = make_float2(m, s);
  }
}

// ---------- tail weighted partial sums (extra token) ----------
__global__ __launch_bounds__(256) void tail_partial_kernel(
    const float* __restrict__ tokens, const u64* __restrict__ keys,
    const float2* __restrict__ stats, float* __restrict__ partials)
{
  int b = blockIdx.y, rb = blockIdx.x, t = threadIdx.x;
  float m = stats[b].x, inv = 1.0f / stats[b].y;
  const u64* kb = keys + (size_t)b*LL + KK + rb*256;
  float a0 = 0.f, a1 = 0.f;
  #pragma unroll 4
  for (int r = 0; r < 256; ++r) {
    u64 kk = kb[r];
    int idx = (LL - 1) - (int)(kk & 0xffffffffu);
    float w = expf(dec_score((u32)(kk >> 32)) - m) * inv;
    const float* src = tokens + ((size_t)b*LL + idx)*CC;
    a0 += w * src[t];
    a1 += w * src[t + 256];
  }
  float* dst = partials + (size_t)(b*8 + rb)*CC;
  dst[t] = a0; dst[t + 256] = a1;
}

// ---------- gather all_tokens (bf16) + per-row LN stats ----------
__global__ __launch_bounds__(256) void gather_ln_kernel(
    const float* __restrict__ tokens, const u64* __restrict__ keys,
    const float* __restrict__ partials,
    u16* __restrict__ allT, float2* __restrict__ rowstats)
{
  int b = blockIdx.y;
  int r = blockIdx.x*4 + (threadIdx.x >> 6);
  int lane = threadIdx.x & 63;
  size_t orow = ((size_t)b*KP + r)*CC;
  int c0 = lane*8;
  if (r > KK) {
    short8 z = {};
    *(short8*)(allT + orow + c0) = z;
    if (lane == 0) rowstats[(size_t)b*KP + r] = make_float2(0.f, 0.f);
    return;
  }
  float x[8];
  if (r < KK) {
    u64 kk = keys[(size_t)b*LL + r];
    int idx = (LL - 1) - (int)(kk & 0xffffffffu);
    const float* src = tokens + ((size_t)b*LL + idx)*CC + c0;
    f32x4 v0 = *(const f32x4*)src;
    f32x4 v1 = *(const f32x4*)(src + 4);
    #pragma unroll
    for (int j = 0; j < 4; ++j) { x[j] = v0[j]; x[j+4] = v1[j]; }
  } else {
    #pragma unroll
    for (int j = 0; j < 8; ++j) {
      float s = 0.f;
      #pragma unroll
      for (int p = 0; p < 8; ++p) s += partials[(size_t)(b*8 + p)*CC + c0 + j];
      x[j] = s;
    }
  }
  float s = 0.f;
  #pragma unroll
  for (int j = 0; j < 8; ++j) s += x[j];
  #pragma unroll
  for (int off = 32; off; off >>= 1) s += __shfl_xor(s, off);
  float mu = s * (1.0f/CC);
  float vs = 0.f;
  #pragma unroll
  for (int j = 0; j < 8; ++j) { float d = x[j] - mu; vs += d*d; }
  #pragma unroll
  for (int off = 32; off; off >>= 1) vs += __shfl_xor(vs, off);
  float rstd = rsqrtf(vs * (1.0f/CC) + 1e-5f);
  short8 raw;
  #pragma unroll
  for (int j = 0; j < 8; ++j) raw[j] = (short)f2bf(x[j]);
  *(short8*)(allT + orow + c0) = raw;
  if (lane == 0) rowstats[(size_t)b*KP + r] = make_float2(mu, rstd);
}

// ---------- weights -> padded transposed bf16, zero sums ----------
__global__ __launch_bounds__(256) void prep_kernel(
    const float* __restrict__ w1, const float* __restrict__ w2,
    u16* __restrict__ w1T, u16* __restrict__ w2T, float* __restrict__ sums)
{
  int id = blockIdx.x*256 + threadIdx.x;
  if (id < HP*CC) {                       // w1T[h][c] = w1[c][h]
    int r = id >> 9, c = id & 511;
    w1T[id] = (r < HH) ? f2bf(w1[c*HH + r]) : (u16)0;
  } else if (id < HP*CC + PPAD*HP) {      // w2T[p][h] = w2[h][p]
    int id2 = id - HP*CC;
    int r = id2 >> 7, c = id2 & 127;
    w2T[id2] = (r < PPQ && c < HH) ? f2bf(w2[(size_t)c*PPQ + r]) : (u16)0;
  } else {
    int id3 = id - HP*CC - PPAD*HP;
    if (id3 < NB*PPAD) sums[id3] = 0.f;
  }
}

// ---------- allT [k][c] -> allTT [c][k] per batch ----------
__global__ __launch_bounds__(256) void transpose_kernel(
    const u16* __restrict__ allT, u16* __restrict__ allTT)
{
  __shared__ u16 t[64][72];
  int b = blockIdx.z;
  int r0 = blockIdx.x*64, c0 = blockIdx.y*64;
  const u16* src = allT + ((size_t)b*KP + r0)*CC + c0;
  int tr = threadIdx.x >> 3, tc = (threadIdx.x & 7)*8;
  #pragma unroll
  for (int i = 0; i < 2; ++i)
    *(short8*)(&t[tr + i*32][tc]) = *(const short8*)(src + (size_t)(tr + i*32)*CC + tc);
  __syncthreads();
  u16* dst = allTT + ((size_t)b*CC + c0)*KP + r0;
  #pragma unroll
  for (int i = 0; i < 2; ++i) {
    int rr = tr + i*32;
    short8 v;
    #pragma unroll
    for (int j = 0; j < 8; ++j) v[j] = (short)t[tc + j][rr];
    *(short8*)(dst + (size_t)rr*KP + tc) = v;
  }
}

// ---------- m97-style 128x128x32 bf16 GEMM, A[M][K] x BT[N][K] ----------
template<int MODE>
__global__ __launch_bounds__(256) void gemm_kernel(
    const u16* __restrict__ A, const u16* __restrict__ Bm, void* __restrict__ Cv,
    const float* __restrict__ bias, const float* __restrict__ scalep,
    const float2* __restrict__ rowstats, const float* __restrict__ gvec,
    const float* __restrict__ bvec, float* __restrict__ sums)
{
  __shared__ u16 As[128*32];
  __shared__ u16 Bs[128*32];
  __shared__ float red[2][128];

  constexpr int KSTEPS = (MODE==0) ? 16 : (MODE==1) ? 4 : 68;
  constexpr int LDA    = (MODE==0) ? CC : (MODE==1) ? HP : KP;
  constexpr int LDB    = (MODE==0) ? CC : (MODE==1) ? HP : KP;

  int chunk = gridDim.x >> 3;
  int lg = (blockIdx.x & 7)*chunk + (blockIdx.x >> 3);
  int b, m0, n0;
  if (MODE == 0)      { b = 0;       m0 = lg*128;           n0 = 0; }
  else if (MODE == 1) { b = lg/119;  int t2 = lg%119; m0 = (t2%17)*128; n0 = (t2/17)*128; }
  else                { b = lg/28;   int t2 = lg%28;  n0 = (t2/7)*128;  m0 = (t2%7)*128; }

  const u16* Ab = A; const u16* Bb = Bm;
  if (MODE == 1) { Ab = A + (size_t)b*KP*HP; }
  if (MODE == 2) { Ab = A + (size_t)b*PPAD*KP; Bb = Bm + (size_t)b*CC*KP; }

  int tid = threadIdx.x, lane = tid & 63, wave = tid >> 6;
  int sr = tid >> 2, sc = (tid & 3)*8;
  int wr = (wave >> 1)*64, wc = (wave & 1)*64;

  float2 st0 = make_float2(0.f,0.f), st1 = st0;
  if (MODE == 0) { st0 = rowstats[m0 + sr]; st1 = rowstats[m0 + 64 + sr]; }

  f32x4 acc[4][4];
  #pragma unroll
  for (int m = 0; m < 4; ++m)
    #pragma unroll
    for (int n = 0; n < 4; ++n) acc[m][n] = (f32x4){0.f,0.f,0.f,0.f};

  for (int ks = 0; ks < KSTEPS; ++ks) {
    int k0 = ks*32;
    if (MODE == 0) {
      const u16* s0 = Ab + (size_t)(m0 + sr)*LDA + k0 + sc;
      short8 v = *(const short8*)s0;
      short8 w = *(const short8*)(s0 + (size_t)64*LDA);
      short8 o1, o2;
      #pragma unroll
      for (int j = 0; j < 8; ++j) {
        int kc = k0 + sc + j;
        float g = gvec[kc], bb = bvec[kc];
        o1[j] = (short)f2bf((bf2f((u16)v[j]) - st0.x)*st0.y*g + bb);
        o2[j] = (short)f2bf((bf2f((u16)w[j]) - st1.x)*st1.y*g + bb);
      }
      *(short8*)(As + tid*8) = o1;
      *(short8*)(As + 2048 + tid*8) = o2;
    } else {
      gload16(Ab + (size_t)(m0 + sr)*LDA + k0 + sc,      As + wave*512);
      gload16(Ab + (size_t)(m0 + 64 + sr)*LDA + k0 + sc, As + 2048 + wave*512);
    }
    gload16(Bb + (size_t)(n0 + sr)*LDB + k0 + sc,      Bs + wave*512);
    gload16(Bb + (size_t)(n0 + 64 + sr)*LDB + k0 + sc, Bs + 2048 + wave*512);
    __syncthreads();
    const u16* ap = As + (wr + (lane & 15))*32 + (lane >> 4)*8;
    const u16* bp = Bs + (wc + (lane & 15))*32 + (lane >> 4)*8;
    short8 af[4], bfr[4];
    #pragma unroll
    for (int m = 0; m < 4; ++m) af[m] = *(const short8*)(ap + m*16*32);
    #pragma unroll
    for (int n = 0; n < 4; ++n) bfr[n] = *(const short8*)(bp + n*16*32);
    #pragma unroll
    for (int n = 0; n < 4; ++n)
      #pragma unroll
      for (int m = 0; m < 4; ++m)
        acc[m][n] = __builtin_amdgcn_mfma_f32_16x16x32_bf16(af[m], bfr[n], acc[m][n], 0, 0, 0);
    __syncthreads();
  }

  if (MODE == 0) {
    #pragma unroll
    for (int m = 0; m < 4; ++m)
      #pragma unroll
      for (int n = 0; n < 4; ++n)
        #pragma unroll
        for (int q = 0; q < 4; ++q) {
          int gm = m0 + wr + m*16 + (lane >> 4)*4 + q;
          int gn = n0 + wc + n*16 + (lane & 15);
          float r = 0.f;
          if (gn < HH) {
            float xx = acc[m][n][q] + bias[gn];
            r = 0.5f*xx*(1.0f + erff(xx*0.70710678118654752f));
          }
          ((u16*)Cv)[(size_t)gm*HP + gn] = f2bf(r);
        }
  } else if (MODE == 1) {
    float sc_ = scalep[0];
    float nsum[4] = {0.f,0.f,0.f,0.f};
    #pragma unroll
    for (int n = 0; n < 4; ++n) {
      int gn = n0 + wc + n*16 + (lane & 15);
      if (gn < PPQ) {
        float bb = bias[gn];
        float s_local = 0.f;
        #pragma unroll
        for (int m = 0; m < 4; ++m)
          #pragma unroll
          for (int q = 0; q < 4; ++q) {
            int gm = m0 + wr + m*16 + (lane >> 4)*4 + q;
            float v2 = (acc[m][n][q] + bb)*sc_;
            float e = __expf(fminf(v2, 20.f));
            ((u16*)Cv)[(size_t)b*PPAD*KP + (size_t)gn*KP + gm] = f2bf(e);
            if (gm <= KK) s_local += e;
          }
        nsum[n] = s_local;
      }
    }
    #pragma unroll
    for (int n = 0; n < 4; ++n) {
      float s = nsum[n];
      s += __shfl_xor(s, 16);
      s += __shfl_xor(s, 32);
      if (lane < 16) red[wave >> 1][wc + n*16 + lane] = s;
    }
    __syncthreads();
    if (tid < 128) {
      int p = n0 + tid;
      if (p < PPQ) atomicAdd(&sums[b*PPAD + p], red[0][tid] + red[1][tid]);
    }
  } else {
    #pragma unroll
    for (int m = 0; m < 4; ++m)
      #pragma unroll
      for (int q = 0; q < 4; ++q) {
        int gm = m0 + wr + m*16 + (lane >> 4)*4 + q;
        if (gm < PPQ) {
          float inv = 1.0f / sums[b*PPAD + gm];
          #pragma unroll
          for (int n = 0; n < 4; ++n) {
            int gn = n0 + wc + n*16 + (lane & 15);
            ((float*)Cv)[(size_t)b*PPQ*CC + (size_t)gm*CC + gn] = acc[m][n][q]*inv;
          }
        }
      }
  }
}

extern "C" void kernel_launch(void* const* d_in, const int* in_sizes, int n_in,
                              void* d_out, int out_size, void* d_ws, size_t ws_size,
                              hipStream_t stream)
{
  const float* tokens = (const float*)d_in[0];
  const float* ax  = (const float*)d_in[1];
  const float* ay  = (const float*)d_in[2];
  const float* ln_g = (const float*)d_in[3];
  const float* ln_b = (const float*)d_in[4];
  const float* w1  = (const float*)d_in[5];
  const float* b1  = (const float*)d_in[6];
  const float* w2  = (const float*)d_in[7];
  const float* b2  = (const float*)d_in[8];
  const float* scale = (const float*)d_in[9];
  float* out_super = (float*)d_out;
  float* out_mask  = out_super + (size_t)NB*PPQ*CC;

  char* ws = (char*)d_ws;
  size_t off = 0;
  u64* keys = (u64*)(ws + off);          off += (size_t)NB*LL*8;
  float2* stats = (float2*)(ws + off);   off += 512;
  float* partials = (float*)(ws + off);  off += (size_t)NB*8*CC*4;
  float2* rowstats = (float2*)(ws + off);off += (size_t)NB*KP*8;
  u16* allT = (u16*)(ws + off);          off += (size_t)NB*KP*CC*2;
  size_t regA_end = off;
  u16* wgtE = (u16*)ws;                  // aliases region A (dead before GEMM1)
  size_t wgtE_end = (size_t)NB*PPAD*KP*2;
  off = (regA_end > wgtE_end) ? regA_end : wgtE_end;
  u16* allTT = (u16*)(ws + off); off += (size_t)NB*CC*KP*2;
  u16* hbuf  = (u16*)(ws + off); off += (size_t)NB*KP*HP*2;
  u16* w1T   = (u16*)(ws + off); off += (size_t)HP*CC*2;
  u16* w2T   = (u16*)(ws + off); off += (size_t)PPAD*HP*2;
  float* sums = (float*)(ws + off); off += (size_t)NB*PPAD*4;
  if (off > ws_size) return;

  prep_kernel<<<928, 256, 0, stream>>>(w1, w2, w1T, w2T, sums);
  sort_kernel<<<NB, 1024, 0, stream>>>(ax, ay, keys, out_mask, stats);
  tail_partial_kernel<<<dim3(8, NB), 256, 0, stream>>>(tokens, keys, stats, partials);
  gather_ln_kernel<<<dim3(KP/4, NB), 256, 0, stream>>>(tokens, keys, partials, allT, rowstats);
  transpose_kernel<<<dim3(KP/64, CC/64, NB), 256, 0, stream>>>(allT, allTT);
  gemm_kernel<0><<<(NB*KP)/128, 256, 0, stream>>>(
      allT, w1T, hbuf, b1, scale, rowstats, ln_g, ln_b, nullptr);
  gemm_kernel<1><<<(KP/128)*(PPAD/128)*NB, 256, 0, stream>>>(
      hbuf, w2T, wgtE, b2, scale, nullptr, nullptr, nullptr, sums);
  gemm_kernel<2><<<(PPAD/128)*(CC/128)*NB, 256, 0, stream>>>(
      wgtE, allTT, out_super, nullptr, scale, nullptr, nullptr, nullptr, sums);
}